// Round 8
// baseline (310.990 us; speedup 1.0000x reference)
//
#include <hip/hip_runtime.h>

#define DEVI static __device__ __forceinline__

using s16x8 = __attribute__((ext_vector_type(8))) short;
using f32x4 = __attribute__((ext_vector_type(4))) float;
using u32x4 = __attribute__((ext_vector_type(4))) unsigned int;

static constexpr int H  = 16;
static constexpr int S  = 1024;
static constexpr int DM = 1024;
static constexpr int NB = 2;          // batch
static constexpr int BS = NB * S;     // 2048
static constexpr long SS  = (long)S * S;
static constexpr long HSS = (long)H * SS;
static constexpr long SDM = (long)S * DM;

DEVI unsigned short f2bf(float f) {
    union { float f; unsigned u; } c; c.f = f;
    c.u += 0x7FFFu + ((c.u >> 16) & 1u);   // RNE
    return (unsigned short)(c.u >> 16);
}
DEVI float bf2f(unsigned short v) {
    union { unsigned u; float f; } c; c.u = ((unsigned)v) << 16;
    return c.f;
}

// async global->LDS, 16 bytes per lane; lds dest = wave-uniform base + lane*16
DEVI void gload16(const unsigned short* g, unsigned short* l) {
    __builtin_amdgcn_global_load_lds(
        (const __attribute__((address_space(1))) unsigned int*)g,
        (__attribute__((address_space(3))) unsigned int*)l, 16, 0, 0);
}

enum { EPI_BFB = 0, EPI_VTB, EPI_PACK, EPI_PACK2, EPI_MASK, EPI_EXP, EPI_SMASK, EPI_BF, EPI_OUT };

// ---------------------------------------------------------------------------
// gemmT: TMxTN-tile, BK=64, single-buffer m97 loop (verified round 5), LDS
// XOR-swizzle via pre-swizzled global source + swizzled ds_read.
// (TM/64)*(TN/64) waves, each wave a 64x64 output (4x4 16x16x32 frags).
// A row-major [m][k]; B row-major [n][k]; out[m][n] = epi(A.B^T).
// EPI_EXP additionally accumulates row-sums of exp into `sums` via atomics.
// EPI_SMASK divides by sums[row]*(row+1) (fused softmax-normalize + mask).
// ---------------------------------------------------------------------------
template<int TM, int TN, int EPI, bool CK, bool CS, bool SWZ, bool REVY>
__global__ __launch_bounds__((TM/64)*(TN/64)*64)
void gemmT(const unsigned short* __restrict__ Aall, long a_sb, long a_sh, int lda,
           const unsigned short* __restrict__ Ball, long b_sb, long b_sh, int ldb,
           void* __restrict__ Oall, void* __restrict__ O2, long o_sb, long o_sh, int ldo,
           const float* __restrict__ bias, int bstride, float* __restrict__ sums,
           int K, int NV)
{
    constexpr int WN = TN / 64, WM = TM / 64, NWV = WM * WN, NTHR = NWV * 64;
    constexpr int IA = (TM * 8) / NTHR, IB = (TN * 8) / NTHR;
    constexpr int IMX = IA > IB ? IA : IB;

    int bx, by, bz;
    if (SWZ) {   // grid must be (8,8,32)
        const int L = (int)blockIdx.x + ((int)blockIdx.y << 3) + ((int)blockIdx.z << 6);
        const int g = L & 7, r = L >> 3;
        bz = g + ((r >> 6) << 3);
        bx = r & 7;
        by = 7 - ((r >> 3) & 7);                 // longest-K first
    } else {
        bx = blockIdx.x;
        by = REVY ? (int)gridDim.y - 1 - (int)blockIdx.y : (int)blockIdx.y;
        bz = blockIdx.z;
    }
    const int m0 = by * TM, n0 = bx * TN;
    if (CS && n0 > m0 + TM - 1) return;
    const int zb = bz >> 4, zh = bz & 15;
    const unsigned short* Ap = Aall + (long)zb * a_sb + (long)zh * a_sh;
    const unsigned short* Bp = Ball + (long)zb * b_sb + (long)zh * b_sh;
    const float* bi = bias + (long)zh * bstride;

    __shared__ alignas(16) unsigned short lA[TM * 64];
    __shared__ alignas(16) unsigned short lB[TN * 64];

    const int tid = threadIdx.x, w = tid >> 6, lane = tid & 63;
    const int lr = lane & 15, lg = lane >> 4;
    const int wm = (w / WN) * 64, wn = (w % WN) * 64;

    const unsigned short* gA[IA]; int loA[IA];
    const unsigned short* gB[IB]; int loB[IB];
#pragma unroll
    for (int i = 0; i < IA; ++i) {
        const int q = i * NTHR + tid, row = q >> 3, slot = q & 7;
        gA[i]  = Ap + (long)(m0 + row) * lda + ((slot ^ (row & 7)) * 8);
        loA[i] = (i * NWV + w) * 512;
    }
#pragma unroll
    for (int i = 0; i < IB; ++i) {
        const int q = i * NTHR + tid, row = q >> 3, slot = q & 7;
        int rb = n0 + row; if (rb >= NV) rb = NV - 1;
        gB[i]  = Bp + (long)rb * ldb + ((slot ^ (row & 7)) * 8);
        loB[i] = (i * NWV + w) * 512;
    }

    int abase[4], axor[4], bbase[4], bxor[4];
#pragma unroll
    for (int f = 0; f < 4; ++f) {
        const int ra = wm + f * 16 + lr;
        abase[f] = ra * 64; axor[f] = (ra & 7) * 8;
        const int rb = wn + f * 16 + lr;
        bbase[f] = rb * 64; bxor[f] = (rb & 7) * 8;
    }

    f32x4 acc[4][4] = {};
    const int Keff = CK ? ((K < m0 + TM) ? K : m0 + TM) : K;

    for (int k0 = 0; k0 < Keff; k0 += 64) {
#pragma unroll
        for (int i = 0; i < IMX; ++i) {           // interleaved A/B issue (round-5 order)
            if (i < IA) gload16(gA[i] + k0, &lA[loA[i]]);
            if (i < IB) gload16(gB[i] + k0, &lB[loB[i]]);
        }
        __syncthreads();
#pragma unroll
        for (int kk = 0; kk < 64; kk += 32) {
            s16x8 af[4], bv[4];
#pragma unroll
            for (int f = 0; f < 4; ++f) {
                af[f] = *reinterpret_cast<const s16x8*>(&lA[abase[f] + ((kk + 8 * lg) ^ axor[f])]);
                bv[f] = *reinterpret_cast<const s16x8*>(&lB[bbase[f] + ((kk + 8 * lg) ^ bxor[f])]);
            }
#pragma unroll
            for (int fm = 0; fm < 4; ++fm)
#pragma unroll
                for (int fn = 0; fn < 4; ++fn)
                    acc[fm][fn] = __builtin_amdgcn_mfma_f32_16x16x32_bf16(af[fm], bv[fn], acc[fm][fn], 0, 0, 0);
        }
        __syncthreads();
    }

    const long obase = (long)zb * o_sb + (long)zh * o_sh;
    if constexpr (EPI == EPI_EXP) {
        // store exp(acc) and accumulate row-sums (fused rowsum)
#pragma unroll
        for (int fm = 0; fm < 4; ++fm) {
            const int t0 = m0 + wm + fm * 16 + lg * 4;
            float es[4] = {0.f, 0.f, 0.f, 0.f};
#pragma unroll
            for (int fn = 0; fn < 4; ++fn) {
                const int gn = n0 + wn + fn * 16 + lr;
#pragma unroll
                for (int r = 0; r < 4; ++r) {
                    const float e = __expf(acc[fm][fn][r]);
                    ((unsigned short*)Oall)[obase + (long)(t0 + r) * ldo + gn] = f2bf(e);
                    es[r] += e;
                }
            }
#pragma unroll
            for (int r = 0; r < 4; ++r) {
                float s = es[r];
                s += __shfl_xor(s, 1); s += __shfl_xor(s, 2);
                s += __shfl_xor(s, 4); s += __shfl_xor(s, 8);
                if (lr == 0) atomicAdd(&sums[(long)bz * S + t0 + r], s);
            }
        }
    } else {
#pragma unroll
        for (int fm = 0; fm < 4; ++fm)
#pragma unroll
            for (int fn = 0; fn < 4; ++fn) {
                const int t0 = m0 + wm + fm * 16 + lg * 4;
                const int gn = n0 + wn + fn * 16 + lr;
                if (gn >= NV) continue;
                if constexpr (EPI == EPI_PACK2) {             // dual store: P and P^T
                    ushort4 pt;
                    unsigned short* o1 = (unsigned short*)Oall;
                    unsigned short* o2 = (unsigned short*)O2;
#pragma unroll
                    for (int r = 0; r < 4; ++r) {
                        float vv = acc[fm][fn][r];
                        vv = vv > 0.f ? vv + 1.f : __expf(vv);   // elu(x)+1
                        const unsigned short b = f2bf(vv);
                        o1[obase + (long)(t0 + r) * ldo + gn] = b;
                        ((unsigned short*)&pt)[r] = b;
                    }
                    *reinterpret_cast<ushort4*>(&o2[obase + (long)gn * ldo + t0]) = pt;
                } else {
#pragma unroll
                    for (int r = 0; r < 4; ++r) {
                        const int gm = t0 + r;
                        float vv = acc[fm][fn][r];
                        const long o = obase + (long)gm * ldo + gn;
                        if constexpr (EPI == EPI_BFB) {
                            ((unsigned short*)Oall)[o] = f2bf(vv + bi[gn]);
                        } else if constexpr (EPI == EPI_VTB) {
                            ((unsigned short*)Oall)[o] = f2bf(vv + bi[gm]);
                        } else if constexpr (EPI == EPI_PACK) {
                            vv = vv > 0.f ? vv + 1.f : __expf(vv);
                            ((unsigned short*)Oall)[o] = f2bf(vv);
                        } else if constexpr (EPI == EPI_MASK) {
                            vv = (gn <= gm) ? vv / (float)(gm + 1) : 0.f;
                            ((unsigned short*)Oall)[o] = f2bf(vv);
                        } else if constexpr (EPI == EPI_SMASK) {
                            vv = (gn <= gm)
                               ? vv / (sums[(long)bz * S + gm] * (float)(gm + 1)) : 0.f;
                            ((unsigned short*)Oall)[o] = f2bf(vv);
                        } else if constexpr (EPI == EPI_BF) {
                            ((unsigned short*)Oall)[o] = f2bf(vv);
                        } else { // EPI_OUT
                            ((float*)Oall)[o] = vv + bi[gn];
                        }
                    }
                }
            }
    }
}

// ---------------------------------------------------------------------------
// packsqk: merged pack2 + sQK (both 128x128-tile, K=64). Grid (8,8,64):
// z-swizzled so each head stays on one XCD; job = high bit (0: P/P^T dual
// store, 1: masked QK^T with causal block-skip).
// ---------------------------------------------------------------------------
__global__ __launch_bounds__(256)
void packsqk(const unsigned short* __restrict__ qh,
             const unsigned short* __restrict__ pbf,
             const unsigned short* __restrict__ kh,
             unsigned short* __restrict__ P, unsigned short* __restrict__ PT,
             unsigned short* __restrict__ SQ)
{
    const int L = (int)blockIdx.x + ((int)blockIdx.y << 3) + ((int)blockIdx.z << 6);
    const int g = L & 7, r = L >> 3;
    const int bzz = g + ((r >> 6) << 3);          // 0..63
    const int bx = r & 7, by = 7 - ((r >> 3) & 7);
    const int job = bzz >> 5, zz = bzz & 31;
    const int m0 = by * 128, n0 = bx * 128;
    if (job && n0 > m0 + 127) return;
    const int zb = zz >> 4, zh = zz & 15;
    const unsigned short* Ap = qh + (long)zb * SDM + zh * 64;
    const unsigned short* Bp = (job ? kh : pbf) + (long)zb * SDM + zh * 64;

    __shared__ alignas(16) unsigned short lA[128 * 64];
    __shared__ alignas(16) unsigned short lB[128 * 64];

    const int tid = threadIdx.x, w = tid >> 6, lane = tid & 63;
    const int lr = lane & 15, lg = lane >> 4;
    const int wm = (w >> 1) << 6, wn = (w & 1) << 6;

#pragma unroll
    for (int i = 0; i < 4; ++i) {
        const int q = i * 256 + tid, row = q >> 3, slot = q & 7;
        const int gs = (slot ^ (row & 7)) * 8;
        gload16(Ap + (long)(m0 + row) * DM + gs, &lA[(i * 4 + w) * 512]);
        gload16(Bp + (long)(n0 + row) * DM + gs, &lB[(i * 4 + w) * 512]);
    }
    __syncthreads();

    f32x4 acc[4][4] = {};
#pragma unroll
    for (int kk = 0; kk < 64; kk += 32) {
        s16x8 af[4], bv[4];
#pragma unroll
        for (int f = 0; f < 4; ++f) {
            const int ra = wm + f * 16 + lr;
            af[f] = *reinterpret_cast<const s16x8*>(&lA[ra * 64 + ((kk + 8 * lg) ^ ((ra & 7) * 8))]);
            const int rb = wn + f * 16 + lr;
            bv[f] = *reinterpret_cast<const s16x8*>(&lB[rb * 64 + ((kk + 8 * lg) ^ ((rb & 7) * 8))]);
        }
#pragma unroll
        for (int fm = 0; fm < 4; ++fm)
#pragma unroll
            for (int fn = 0; fn < 4; ++fn)
                acc[fm][fn] = __builtin_amdgcn_mfma_f32_16x16x32_bf16(af[fm], bv[fn], acc[fm][fn], 0, 0, 0);
    }

    const long obase = (long)zz * SS;
#pragma unroll
    for (int fm = 0; fm < 4; ++fm)
#pragma unroll
        for (int fn = 0; fn < 4; ++fn) {
            const int t0 = m0 + wm + fm * 16 + lg * 4;
            const int gn = n0 + wn + fn * 16 + lr;
            if (job == 0) {                        // P and P^T dual store
                ushort4 pt;
#pragma unroll
                for (int rr = 0; rr < 4; ++rr) {
                    float vv = acc[fm][fn][rr];
                    vv = vv > 0.f ? vv + 1.f : __expf(vv);
                    const unsigned short b = f2bf(vv);
                    P[obase + (long)(t0 + rr) * S + gn] = b;
                    ((unsigned short*)&pt)[rr] = b;
                }
                *reinterpret_cast<ushort4*>(&PT[obase + (long)gn * S + t0]) = pt;
            } else {                               // masked QK^T
#pragma unroll
                for (int rr = 0; rr < 4; ++rr) {
                    const int gm = t0 + rr;
                    float vv = acc[fm][fn][rr];
                    vv = (gn <= gm) ? vv / (float)(gm + 1) : 0.f;
                    SQ[obase + (long)gm * S + gn] = f2bf(vv);
                }
            }
        }
}

// ---------------------------------------------------------------------------
// prep: merged input casts (z=0..3), weight transposes (z=4..7), bias pack (z=8)
// grid (2048, 1, 9) x 256 threads
// ---------------------------------------------------------------------------
__global__ __launch_bounds__(256)
void prep(const float* __restrict__ q_in, const float* __restrict__ k_in,
          const float* __restrict__ v_in, const float* __restrict__ p_in,
          const float* __restrict__ wq, const float* __restrict__ wk,
          const float* __restrict__ wv, const float* __restrict__ wc,
          const float* __restrict__ wqb, const float* __restrict__ wkb,
          unsigned short* __restrict__ qbf, unsigned short* __restrict__ wqT,
          float* __restrict__ bq2, int n4)
{
    const int z = blockIdx.z, bx = blockIdx.x, tid = threadIdx.x;
    if (z < 4) {
        const int i = bx * 256 + tid;
        if (i >= n4) return;
        const float* s = (z == 0) ? q_in : (z == 1) ? k_in : (z == 2) ? v_in : p_in;
        float4 x = reinterpret_cast<const float4*>(s)[i];
        ushort4 o; o.x = f2bf(x.x); o.y = f2bf(x.y); o.z = f2bf(x.z); o.w = f2bf(x.w);
        reinterpret_cast<ushort4*>(qbf + (size_t)z * n4 * 4)[i] = o;
    } else if (z < 8) {
        if (bx >= 256) return;
        __shared__ unsigned short t[64][72];
        const int zz = z - 4;
        const float* src = (zz == 0) ? wq : (zz == 1) ? wk : (zz == 2) ? wv : wc;
        const float scale = (zz == 0) ? 0.125f : 1.0f;
        unsigned short* dst = wqT + (size_t)zz * DM * DM;
        const int r0 = (bx >> 4) * 64, c0 = (bx & 15) * 64;
        const int lrow = tid >> 2, lseg = (tid & 3) << 4;
        const float4* g4 = reinterpret_cast<const float4*>(src + (long)(r0 + lrow) * DM + c0 + lseg);
        alignas(16) unsigned short tmp[16];
#pragma unroll
        for (int qq = 0; qq < 4; ++qq) {
            float4 x = g4[qq];
            tmp[4*qq+0] = f2bf(x.x * scale); tmp[4*qq+1] = f2bf(x.y * scale);
            tmp[4*qq+2] = f2bf(x.z * scale); tmp[4*qq+3] = f2bf(x.w * scale);
        }
#pragma unroll
        for (int j = 0; j < 16; ++j) t[lrow][lseg + j] = tmp[j];
        __syncthreads();
#pragma unroll
        for (int j = 0; j < 16; ++j) tmp[j] = t[lseg + j][lrow];
        unsigned short* d = dst + (long)(c0 + lrow) * DM + r0 + lseg;
        *reinterpret_cast<u32x4*>(d)     = *reinterpret_cast<const u32x4*>(tmp);
        *reinterpret_cast<u32x4*>(d + 8) = *reinterpret_cast<const u32x4*>(tmp + 8);
    } else {
        if (bx >= 4) return;
        const int i = bx * 256 + tid;
        if (i < DM) { bq2[i] = wqb[i] * 0.125f; bq2[DM + i] = wkb[i]; }
    }
}

extern "C" void kernel_launch(void* const* d_in, const int* in_sizes, int n_in,
                              void* d_out, int out_size, void* d_ws, size_t ws_size,
                              hipStream_t stream)
{
    (void)in_sizes; (void)n_in; (void)out_size;
    const float* v_in = (const float*)d_in[0];
    const float* k_in = (const float*)d_in[1];
    const float* q_in = (const float*)d_in[2];
    const float* p_in = (const float*)d_in[3];
    const float* wq   = (const float*)d_in[4];
    const float* wqb  = (const float*)d_in[5];
    const float* wk   = (const float*)d_in[6];
    const float* wkb  = (const float*)d_in[7];
    const float* wvw  = (const float*)d_in[8];
    const float* wvb  = (const float*)d_in[9];
    const float* wc   = (const float*)d_in[10];
    const float* wcb  = (const float*)d_in[11];
    float* out = (float*)d_out;

    char* ws = (char*)d_ws;
    size_t off = 0;
    auto take = [&](size_t n) { char* p = ws + off; off += (n + 255) & ~(size_t)255; return p; };
    unsigned short* qbf = (unsigned short*)take((size_t)BS * DM * 2);  // qbf..pbf contiguous
    unsigned short* kbf = (unsigned short*)take((size_t)BS * DM * 2);
    unsigned short* vbf = (unsigned short*)take((size_t)BS * DM * 2);
    unsigned short* pbf = (unsigned short*)take((size_t)BS * DM * 2);
    unsigned short* wqT = (unsigned short*)take((size_t)DM * DM * 2);  // wqT..wcT contiguous
    unsigned short* wkT = (unsigned short*)take((size_t)DM * DM * 2);
    unsigned short* wvT = (unsigned short*)take((size_t)DM * DM * 2);
    unsigned short* wcT = (unsigned short*)take((size_t)DM * DM * 2);
    float*          bq2 = (float*)take((size_t)2 * DM * 4);
    float*          sums= (float*)take((size_t)NB * H * S * 4);
    unsigned short* qh  = (unsigned short*)take((size_t)BS * DM * 2);  // qh,kh contiguous
    unsigned short* kh  = (unsigned short*)take((size_t)BS * DM * 2);
    unsigned short* vhT = (unsigned short*)take((size_t)BS * DM * 2);
    unsigned short* ao  = (unsigned short*)take((size_t)BS * DM * 2);
    const size_t ssz = (size_t)NB * HSS * 2;
    unsigned short* B1 = (unsigned short*)take(ssz);
    unsigned short* B2 = (unsigned short*)take(ssz);
    unsigned short* B3 = (unsigned short*)take(ssz);
    const bool dual = (ws_size >= off + ssz);          // 4th S x S buffer fits?
    unsigned short* B4 = dual ? (unsigned short*)take(ssz) : nullptr;
    (void)kbf; (void)wkT;

    const int n4 = BS * DM / 4;
    const dim3 b256(256), b128(128);

    hipMemsetAsync(sums, 0, (size_t)NB * H * S * 4, stream);
    prep<<<dim3(n4 / 256, 1, 9), b256, 0, stream>>>(
        q_in, k_in, v_in, p_in, wq, wk, wvw, wc, wqb, wkb, qbf, wqT, bq2, n4);

    // q,k projections merged over z (alpha folded into wqT/bq2), 64x128 tiles
    gemmT<64,128,EPI_BFB,false,false,false,false><<<dim3(8, 32, 2), b128, 0, stream>>>(
        qbf, 0, (long)BS*DM, DM,  wqT, 0, (long)DM*DM, DM,  qh, nullptr, 0, (long)BS*DM, DM,
        bq2, DM, nullptr, DM, DM);
    // vhT[b][dm][t] = (v@wv + b)^T, 64x128 tiles
    gemmT<64,128,EPI_VTB,false,false,false,false><<<dim3(8, 16, 2), b128, 0, stream>>>(
        wvT, 0, 0, DM,  vbf, 0, SDM, DM,  vhT, nullptr, 0, (long)DM*S, S,
        wvb, 0, nullptr, DM, S);

    unsigned short *ptbuf, *pbuf, *ebuf, *s2buf, *sqkbuf;
    if (dual) {
        // merged: P -> B1, P^T -> B2, sQK -> B3 in ONE launch
        packsqk<<<dim3(8, 8, 64), b256, 0, stream>>>(qh, pbf, kh, B1, B2, B3);
        pbuf = B1; ptbuf = B2; sqkbuf = B3; ebuf = B4; s2buf = B3;
    } else {
        gemmT<128,128,EPI_PACK,false,false,true,false><<<dim3(8, 8, 32), b256, 0, stream>>>(
            pbf, SDM, 64, DM,  qh, SDM, 64, DM,  B1, nullptr, HSS, SS, S,  wvb, 0, nullptr, 64, S);
        ptbuf = B1; sqkbuf = B2; ebuf = B3; pbuf = B1; s2buf = B2;
        gemmT<128,128,EPI_MASK,false,true,true,false><<<dim3(8, 8, 32), b256, 0, stream>>>(
            qh, SDM, 64, DM,  kh, SDM, 64, DM,  sqkbuf, nullptr, HSS, SS, S,  wvb, 0, nullptr, 64, S);
    }
    // E = exp(sQK @ P) with fused row-sums, causal-K -> ebuf (bf16)
    gemmT<128,128,EPI_EXP,true,false,true,false><<<dim3(8, 8, 32), b256, 0, stream>>>(
        sqkbuf, HSS, SS, S,  ptbuf, HSS, SS, S,  ebuf, nullptr, HSS, SS, S,
        wvb, 0, sums, S, S);
    if (!dual) {
        // pack[t][s] = elu(qh.ph)+1 -> B1 (packT dead)
        gemmT<128,128,EPI_PACK,false,false,true,false><<<dim3(8, 8, 32), b256, 0, stream>>>(
            qh, SDM, 64, DM,  pbf, SDM, 64, DM,  B1, nullptr, HSS, SS, S,  wvb, 0, nullptr, 64, S);
    }
    // s2[t][s] = (E[t,:].P[s,:]) / (sums[t]*(t+1)), causal-skip (full K) -> s2buf
    gemmT<128,128,EPI_SMASK,false,true,true,false><<<dim3(8, 8, 32), b256, 0, stream>>>(
        ebuf, HSS, SS, S,  pbuf, HSS, SS, S,  s2buf, nullptr, HSS, SS, S,
        nullptr, 0, sums, S, S);
    // attn_out[t][d] = s2 @ vh (B = vhT head-slice [d][s]), 128x64 tiles, causal-K
    gemmT<128,64,EPI_BF,true,false,false,true><<<dim3(1, 8, 32), b128, 0, stream>>>(
        s2buf, HSS, SS, S,  vhT, (long)DM*S, (long)64*S, S,  ao, nullptr, SDM, 64, DM,
        wvb, 0, nullptr, S, 64);
    // out = ao @ wc + b (f32), 64x128 tiles
    gemmT<64,128,EPI_OUT,false,false,false,false><<<dim3(8, 32, 1), b128, 0, stream>>>(
        ao, 0, 0, DM,  wcT, 0, 0, DM,  out, nullptr, 0, 0, DM,  wcb, 0, nullptr, DM, DM);
}